// Round 6
// baseline (400.995 us; speedup 1.0000x reference)
//
#include <hip/hip_runtime.h>

// ---------------------------------------------------------------------------
// VAEAttention: GroupNorm(32) -> q,k,v 1x1 conv -> full spatial attention
// (N=4096 tokens, d=512) -> out proj -> +residual.   B=4, H=W=64, C=512.
// R13: k_gemm_s -> mx32_db core (2x fp8 rate; byte-identical to the PV core
// that passed R12) + low-liveness epilogue: per-r immediate rowsum (R11-
// verified indexing) + one-pass 128x144 staging store (R11-verified), NO
// launch-bounds cap (R11's spill cause) and NO rsum[16] arrays (R10's
// pressure cause).  Everything else identical to R12 (322us).
// ---------------------------------------------------------------------------

typedef __bf16 bf16x8 __attribute__((ext_vector_type(8)));
typedef __bf16 bf16x4 __attribute__((ext_vector_type(4)));
typedef float  f32x4  __attribute__((ext_vector_type(4)));
typedef float  f32x16 __attribute__((ext_vector_type(16)));
typedef int    i32x8  __attribute__((ext_vector_type(8)));

#define GLDS(gp, lp) __builtin_amdgcn_global_load_lds( \
    (const __attribute__((address_space(1))) void*)(gp), \
    (__attribute__((address_space(3))) void*)(lp), 16, 0, 0)

// fp32 -> fp8 e4m3 (OCP on gfx950), RNE via HW cvt. Low byte of packed pair.
__device__ __forceinline__ unsigned char f2fp8(float x) {
  int p = __builtin_amdgcn_cvt_pk_fp8_f32(x, 0.f, 0, false);
  return (unsigned char)(p & 0xff);
}

// ---------------------------------------------------------------------------
// GroupNorm stats: one block per (b,g).  64*64 pixels * 16 channels = 65536.
// ---------------------------------------------------------------------------
__global__ __launch_bounds__(256) void k_gnstats(
    const float* __restrict__ x, float* __restrict__ meanv, float* __restrict__ rstdv)
{
  const int bg = blockIdx.x;            // b*32+g
  const int b = bg >> 5, g = bg & 31;
  const float* base = x + (size_t)b * 2097152 + g * 16;
  float s = 0.f, ss = 0.f;
  for (int p = threadIdx.x; p < 4096; p += 256) {
    const float4* rp = (const float4*)(base + (size_t)p * 512);
#pragma unroll
    for (int j = 0; j < 4; ++j) {
      float4 t = rp[j];
      s  += t.x + t.y + t.z + t.w;
      ss += t.x * t.x + t.y * t.y + t.z * t.z + t.w * t.w;
    }
  }
  for (int off = 32; off; off >>= 1) { s += __shfl_xor(s, off, 64); ss += __shfl_xor(ss, off, 64); }
  __shared__ float rs[4], rss[4];
  if ((threadIdx.x & 63) == 0) { rs[threadIdx.x >> 6] = s; rss[threadIdx.x >> 6] = ss; }
  __syncthreads();
  if (threadIdx.x == 0) {
    float S = rs[0] + rs[1] + rs[2] + rs[3];
    float SS = rss[0] + rss[1] + rss[2] + rss[3];
    float m = S * (1.f / 65536.f);
    float var = SS * (1.f / 65536.f) - m * m;
    meanv[bg] = m;
    rstdv[bg] = rsqrtf(var + 1e-6f);
  }
}

// ---------------------------------------------------------------------------
// Normalize + affine + cast to bf16.  8.4M elements, float4 per thread.
// ---------------------------------------------------------------------------
__global__ __launch_bounds__(256) void k_norm(
    const float* __restrict__ x, const float* __restrict__ meanv,
    const float* __restrict__ rstdv, const float* __restrict__ gamma,
    const float* __restrict__ beta, __bf16* __restrict__ x16)
{
  size_t i4 = (size_t)blockIdx.x * 256 + threadIdx.x;  // 0..2097151
  size_t i = i4 * 4;
  int c = (int)(i & 511);
  int bg = (int)(i >> 21) * 32 + (c >> 4);
  float m = meanv[bg], r = rstdv[bg];
  float4 xv = *(const float4*)(x + i);
  float4 gv = *(const float4*)(gamma + c);
  float4 bv = *(const float4*)(beta + c);
  bf16x4 o;
  o[0] = (__bf16)((xv.x - m) * r * gv.x + bv.x);
  o[1] = (__bf16)((xv.y - m) * r * gv.y + bv.y);
  o[2] = (__bf16)((xv.z - m) * r * gv.z + bv.z);
  o[3] = (__bf16)((xv.w - m) * r * gv.w + bv.w);
  *(bf16x4*)(x16 + i) = o;
}

// ---------------------------------------------------------------------------
// Weight prep: Bt layouts (row = output dim, contiguous K).
// wqkvt[1536][512] (wq scaled by 1/sqrt(512)), biasqkv[1536], wot[512][512].
// Also zeroes the row-sum buffer l[16384] (tail of index range).
// ---------------------------------------------------------------------------
__global__ __launch_bounds__(256) void k_prep(
    const float* __restrict__ wq, const float* __restrict__ bq,
    const float* __restrict__ wk, const float* __restrict__ bk,
    const float* __restrict__ wv, const float* __restrict__ bv,
    const float* __restrict__ wo,
    __bf16* __restrict__ wqkvt, float* __restrict__ biasqkv, __bf16* __restrict__ wot,
    float* __restrict__ lsum)
{
  const float sc = 0.04419417382415922f;  // 1/sqrt(512)
  int idx = blockIdx.x * 256 + threadIdx.x;
  if (idx < 786432) {
    int d = idx >> 9, c = idx & 511;
    float v;
    if (d < 512)       v = wq[c * 512 + d] * sc;
    else if (d < 1024) v = wk[c * 512 + d - 512];
    else               v = wv[c * 512 + d - 1024];
    wqkvt[idx] = (__bf16)v;
  } else if (idx < 786432 + 262144) {
    int j = idx - 786432;
    int d = j >> 9, c = j & 511;
    wot[j] = (__bf16)wo[c * 512 + d];
  } else if (idx < 786432 + 262144 + 1536) {
    int d = idx - 786432 - 262144;
    float v = (d < 512) ? bq[d] * sc : (d < 1024 ? bk[d - 512] : bv[d - 1024]);
    biasqkv[d] = v;
  } else if (idx < 786432 + 262144 + 1536 + 16384) {
    lsum[idx - 786432 - 262144 - 1536] = 0.f;
  }
}

// ---------------------------------------------------------------------------
// GEMM core (bf16, XOR-swizzled LDS): C[BM,BN] += A[m0..,K] * Bt[n0..,K]^T.
// (unchanged — used by qkv / out projections)
// ---------------------------------------------------------------------------
template <int BM, int BN>
__device__ __forceinline__ void gemm_core(
    const __bf16* __restrict__ A, const __bf16* __restrict__ Bt, int K,
    int m0, int n0, __bf16* As, __bf16* Bs, f32x4 (&acc)[BM / 32][BN / 32])
{
  constexpr int FM = BM / 32, FN = BN / 32;
  const int tid = threadIdx.x;
  const int lane = tid & 63;
  const int wave = tid >> 6;
  const int wm = wave >> 1, wn = wave & 1;
  const int l15 = lane & 15, l4 = lane >> 4;
  const int sw = (l15 >> 1) & 3;            // read-side chunk swizzle

  for (int kt = 0; kt < K; kt += 32) {
#pragma unroll
    for (int i = 0; i < BM / 64; ++i) {
      int ci = i * 256 + tid;
      int row = ci >> 2, kc = ci & 3;
      int kcs = kc ^ ((row >> 1) & 3);       // swizzled source chunk
      const __bf16* g = A + (size_t)(m0 + row) * K + kt + kcs * 8;
      __bf16* l = As + i * 2048 + wave * 512;  // wave-uniform LDS base
      GLDS(g, l);
    }
#pragma unroll
    for (int i = 0; i < BN / 64; ++i) {
      int ci = i * 256 + tid;
      int row = ci >> 2, kc = ci & 3;
      int kcs = kc ^ ((row >> 1) & 3);
      const __bf16* g = Bt + (size_t)(n0 + row) * K + kt + kcs * 8;
      __bf16* l = Bs + i * 2048 + wave * 512;
      GLDS(g, l);
    }
    __syncthreads();  // drains vmcnt(0) -> LDS tiles valid
    bf16x8 af[FM], bfr[FN];
#pragma unroll
    for (int mi = 0; mi < FM; ++mi)
      af[mi] = *(const bf16x8*)&As[(wm * (BM / 2) + mi * 16 + l15) * 32 + (l4 ^ sw) * 8];
#pragma unroll
    for (int ni = 0; ni < FN; ++ni)
      bfr[ni] = *(const bf16x8*)&Bs[(wn * (BN / 2) + ni * 16 + l15) * 32 + (l4 ^ sw) * 8];
#pragma unroll
    for (int mi = 0; mi < FM; ++mi)
#pragma unroll
      for (int ni = 0; ni < FN; ++ni)
        acc[mi][ni] = __builtin_amdgcn_mfma_f32_16x16x32_bf16(af[mi], bfr[ni], acc[mi][ni], 0, 0, 0);
    __syncthreads();  // protect LDS before next stage
  }
}

// ---------------------------------------------------------------------------
// GEMM core (MX fp8, 32x32x64, scale=1.0, 2-phase double-buffer):
// prologue stages tile 0; per tile: STAGE(t+1) -> ds_read+MFMA(t) -> ONE
// barrier.  One 32x32x64 scaled MFMA per fragment pair at 2x the fp8 rate.
// HW-verified (R9/R10 math; R12 dbuf form on PV).
// A-operand: lane l holds row (l&31), k-bytes [ (l>>5)*32 , +32 ).
// C/D (m74/m101): col = lane&31, row = (r&3)+8*(r>>2)+4*(l>>5).
// ---------------------------------------------------------------------------
template <int BM, int BN>
__device__ __forceinline__ void gemm_core_mx32_db(
    const unsigned char* __restrict__ A, const unsigned char* __restrict__ Bt,
    int K, int m0, int n0, unsigned char* smem,
    f32x16 (&acc)[BM / 64][BN / 64])
{
  constexpr int FM = BM / 64, FN = BN / 64;
  constexpr int ASZ = (BM / 64) * 4096;
  constexpr int BSZ = (BN / 64) * 4096;
  constexpr int BUF = ASZ + BSZ;
  const int tid = threadIdx.x;
  const int lane = tid & 63;
  const int wave = tid >> 6;
  const int wm = wave >> 1, wn = wave & 1;
  const int l31 = lane & 31, h = lane >> 5;   // h: k-block of 32 bytes
  const int nt = K >> 6;

  auto stage = [&](int b, int kt) {
    unsigned char* As_ = smem + b * BUF;
    unsigned char* Bs_ = As_ + ASZ;
#pragma unroll
    for (int i = 0; i < BM / 64; ++i) {
      int ci = i * 256 + tid;
      int row = ci >> 2, kc = ci & 3;
      int kcs = (kc ^ ((row >> 1) & 3)) * 16;
      GLDS(A + (size_t)(m0 + row) * K + kt + kcs, As_ + i * 4096 + wave * 1024);
    }
#pragma unroll
    for (int i = 0; i < BN / 64; ++i) {
      int ci = i * 256 + tid;
      int row = ci >> 2, kc = ci & 3;
      int kcs = (kc ^ ((row >> 1) & 3)) * 16;
      GLDS(Bt + (size_t)(n0 + row) * K + kt + kcs, Bs_ + i * 4096 + wave * 1024);
    }
  };

  stage(0, 0);
  __syncthreads();
  for (int t = 0; t < nt; ++t) {
    if (t + 1 < nt) stage((t + 1) & 1, (t + 1) * 64);
    const unsigned char* As = smem + (t & 1) * BUF;
    const unsigned char* Bs = As + ASZ;
    i32x8 af[FM], bfr[FN];
#pragma unroll
    for (int mi = 0; mi < FM; ++mi) {
      int row = wm * (BM / 2) + mi * 32 + l31;
      int s = (row >> 1) & 3;
      int c0 = (2 * h) ^ s, c1 = (2 * h + 1) ^ s;   // two 16B chunks = 32B of k
      uint4 u0 = *(const uint4*)&As[row * 64 + c0 * 16];
      uint4 u1 = *(const uint4*)&As[row * 64 + c1 * 16];
      af[mi][0] = (int)u0.x; af[mi][1] = (int)u0.y; af[mi][2] = (int)u0.z; af[mi][3] = (int)u0.w;
      af[mi][4] = (int)u1.x; af[mi][5] = (int)u1.y; af[mi][6] = (int)u1.z; af[mi][7] = (int)u1.w;
    }
#pragma unroll
    for (int ni = 0; ni < FN; ++ni) {
      int row = wn * (BN / 2) + ni * 32 + l31;
      int s = (row >> 1) & 3;
      int c0 = (2 * h) ^ s, c1 = (2 * h + 1) ^ s;
      uint4 u0 = *(const uint4*)&Bs[row * 64 + c0 * 16];
      uint4 u1 = *(const uint4*)&Bs[row * 64 + c1 * 16];
      bfr[ni][0] = (int)u0.x; bfr[ni][1] = (int)u0.y; bfr[ni][2] = (int)u0.z; bfr[ni][3] = (int)u0.w;
      bfr[ni][4] = (int)u1.x; bfr[ni][5] = (int)u1.y; bfr[ni][6] = (int)u1.z; bfr[ni][7] = (int)u1.w;
    }
#pragma unroll
    for (int mi = 0; mi < FM; ++mi)
#pragma unroll
      for (int ni = 0; ni < FN; ++ni)
        acc[mi][ni] = __builtin_amdgcn_mfma_scale_f32_32x32x64_f8f6f4(
            af[mi], bfr[ni], acc[mi][ni],
            0, 0,                       // cbsz/blgp = fp8 e4m3
            0, 0x7f7f7f7f,              // scale_a: e8m0 = 1.0
            0, 0x7f7f7f7f);             // scale_b: e8m0 = 1.0
    __syncthreads();
  }
}

// ---------------------------------------------------------------------------
// QKV GEMM: X[16384][512] @ Wqkv^T.  q,k stored fp8 row-major (scores GEMM
// is fp8); v transposed + fp8 (vt8[b][c][n]) for the fp8 PV GEMM.  Bias fused.
// ---------------------------------------------------------------------------
__global__ __launch_bounds__(256) void k_gemm_qkv(
    const __bf16* __restrict__ X, const __bf16* __restrict__ Wt,
    const float* __restrict__ bias, unsigned char* __restrict__ q8,
    unsigned char* __restrict__ k8, unsigned char* __restrict__ vt8)
{
  __shared__ __align__(16) __bf16 As[128 * 32], Bs[128 * 32];
  f32x4 acc[4][4];
#pragma unroll
  for (int i = 0; i < 4; ++i)
#pragma unroll
    for (int j = 0; j < 4; ++j)
#pragma unroll
      for (int r = 0; r < 4; ++r) acc[i][j][r] = 0.f;
  const int m0 = blockIdx.x * 128, n0 = blockIdx.y * 128;
  gemm_core<128, 128>(X, Wt, 512, m0, n0, As, Bs, acc);

  const int lane = threadIdx.x & 63, wave = threadIdx.x >> 6;
  const int wm = wave >> 1, wn = wave & 1, l15 = lane & 15, l4 = lane >> 4;
#pragma unroll
  for (int mi = 0; mi < 4; ++mi) {
#pragma unroll
    for (int ni = 0; ni < 4; ++ni) {
      int gcol = n0 + wn * 64 + ni * 16 + l15;
      float bb = bias[gcol];
#pragma unroll
      for (int r = 0; r < 4; ++r) {
        int grow = m0 + wm * 64 + mi * 16 + l4 * 4 + r;
        float val = acc[mi][ni][r] + bb;
        int b = grow >> 12, n = grow & 4095;
        if (gcol < 512)
          q8[(size_t)grow * 512 + gcol] = f2fp8(val);
        else if (gcol < 1024)
          k8[(size_t)grow * 512 + (gcol - 512)] = f2fp8(val);
        else
          vt8[((size_t)b * 512 + (gcol - 1024)) * 4096 + n] = f2fp8(val);
      }
    }
  }
}

// ---------------------------------------------------------------------------
// Scores GEMM (MX fp8 32x32x64, BK=64, 2-phase dbuf) + max-free softmax
// numerator, batched over z: P[b][n][m] = exp(q.k) stored fp8 e4m3;
// lsum[b][n] += fp32 row sums.
// Low-liveness epilogue (R11-verified indexing, no launch-bounds cap):
//  - per-r immediate rowsum: one scalar live, 5-shuffle reduce over 32 cols
//  - one-pass fp8 conversion into 128x144 LDS tile (reuses dbuf smem)
//  - 16B-coalesced stores
// C/D: local col = wn*64+ni*32+(lane&31),
//      local row = wm*64+mi*32+(r&3)+8*(r>>2)+4*(lane>>5).
// ---------------------------------------------------------------------------
__global__ __launch_bounds__(256) void k_gemm_s(
    const unsigned char* __restrict__ qall, const unsigned char* __restrict__ kall,
    unsigned char* __restrict__ S8all, float* __restrict__ lsum)
{
  __shared__ __align__(16) unsigned char smem[32768];  // 2x(8K As + 8K Bs); reused as 128x144 staging
  f32x16 acc[2][2];
#pragma unroll
  for (int i = 0; i < 2; ++i)
#pragma unroll
    for (int j = 0; j < 2; ++j)
#pragma unroll
      for (int r = 0; r < 16; ++r) acc[i][j][r] = 0.f;

  // supertile swizzle: 1024 blocks/batch -> 16 groups of 64 (8x8)
  const int b = blockIdx.z;
  const int flat = blockIdx.x + (blockIdx.y << 5);
  const int gx = flat & 7, gy = (flat >> 3) & 7, grp = flat >> 6;
  const int bx = (grp & 3) * 8 + gx, by = (grp >> 2) * 8 + gy;
  const int m0 = bx * 128, n0 = by * 128;

  const unsigned char* q = qall + (size_t)b * 4096 * 512;
  const unsigned char* k = kall + (size_t)b * 4096 * 512;
  unsigned char* S8 = S8all + (size_t)b * 4096 * 4096;
  gemm_core_mx32_db<128, 128>(q, k, 512, m0, n0, smem, acc);

  const int lane = threadIdx.x & 63, wave = threadIdx.x >> 6;
  const int wm = wave >> 1, wn = wave & 1, l31 = lane & 31, h = lane >> 5;

  // exp in place + per-r immediate row-sum reduce (pre-fp8-rounding sums).
  // Shuffle masks 1..16 keep bit5 fixed -> reduce spans the 32 cols of each
  // half-wave; lanes 0 and 32 hold sums for their rows (h=0/1).
#pragma unroll
  for (int mi = 0; mi < 2; ++mi) {
#pragma unroll
    for (int r = 0; r < 16; ++r) {
      float a0 = __expf(acc[mi][0][r]);
      float a1 = __expf(acc[mi][1][r]);
      acc[mi][0][r] = a0;
      acc[mi][1][r] = a1;
      float t = a0 + a1;
#pragma unroll
      for (int off = 1; off < 32; off <<= 1) t += __shfl_xor(t, off, 64);
      if (l31 == 0) {
        int grow = m0 + wm * 64 + mi * 32 + (r & 3) + 8 * (r >> 2) + 4 * h;
        atomicAdd(&lsum[b * 4096 + grow], t);
      }
    }
  }

  // One-pass staging: convert all 64 values to fp8 into t8[128][144].
  // (core's final barrier already synced all LDS readers; safe to overwrite)
  unsigned char* t8 = smem;
#pragma unroll
  for (int mi = 0; mi < 2; ++mi)
#pragma unroll
    for (int ni = 0; ni < 2; ++ni) {
      int lcol = wn * 64 + ni * 32 + l31;
#pragma unroll
      for (int r = 0; r < 16; ++r) {
        int lrow = wm * 64 + mi * 32 + (r & 3) + 8 * (r >> 2) + 4 * h;
        t8[lrow * 144 + lcol] = f2fp8(acc[mi][ni][r]);
      }
    }
  __syncthreads();
  // store 128 rows x 128 B: 1024 chunks of 16B, 4 per thread
#pragma unroll
  for (int j = 0; j < 4; ++j) {
    int idx = j * 256 + threadIdx.x;
    int crow = idx >> 3, ccol = (idx & 7) * 16;
    uint4 v = *(const uint4*)&t8[crow * 144 + ccol];
    *(uint4*)&S8[(size_t)(m0 + crow) * 4096 + n0 + ccol] = v;
  }
}

// ---------------------------------------------------------------------------
// PV GEMM (MX fp8 32x32x64, BK=64, 2-phase dbuf), batched over z:
// O[b,n,c] = (sum_m P[b,n,m] * vt[b,c,m]) / l[b,n].
// ---------------------------------------------------------------------------
__global__ __launch_bounds__(256) void k_gemm_pv(
    const unsigned char* __restrict__ S8all, const unsigned char* __restrict__ vt8all,
    const float* __restrict__ lsum, __bf16* __restrict__ attn)
{
  __shared__ __align__(16) unsigned char smem[32768];  // 2 x (8KB As + 8KB Bs)
  f32x16 acc[2][2];
#pragma unroll
  for (int i = 0; i < 2; ++i)
#pragma unroll
    for (int j = 0; j < 2; ++j)
#pragma unroll
      for (int r = 0; r < 16; ++r) acc[i][j][r] = 0.f;
  const int b = blockIdx.z;
  const unsigned char* P = S8all + (size_t)b * 4096 * 4096;
  const unsigned char* V = vt8all + (size_t)b * 512 * 4096;
  __bf16* O = attn + (size_t)b * 4096 * 512;
  const int m0 = blockIdx.x * 128, n0 = blockIdx.y * 128;
  gemm_core_mx32_db<128, 128>(P, V, 4096, m0, n0, smem, acc);

  const int lane = threadIdx.x & 63, wave = threadIdx.x >> 6;
  const int wm = wave >> 1, wn = wave & 1, l31 = lane & 31, h = lane >> 5;
#pragma unroll
  for (int mi = 0; mi < 2; ++mi)
#pragma unroll
    for (int ni = 0; ni < 2; ++ni) {
      int gcol = n0 + wn * 64 + ni * 32 + l31;
#pragma unroll
      for (int r = 0; r < 16; ++r) {
        int grow = m0 + wm * 64 + mi * 32 + (r & 3) + 8 * (r >> 2) + 4 * h;
        float inv = 1.f / lsum[b * 4096 + grow];
        O[(size_t)grow * 512 + gcol] = (__bf16)(acc[mi][ni][r] * inv);
      }
    }
}

// ---------------------------------------------------------------------------
// Output projection + bias + residual, fp32 store to d_out.
// ---------------------------------------------------------------------------
__global__ __launch_bounds__(256) void k_gemm_out(
    const __bf16* __restrict__ A, const __bf16* __restrict__ Wot,
    const float* __restrict__ bo, const float* __restrict__ resid, float* __restrict__ out)
{
  __shared__ __align__(16) __bf16 As[128 * 32], Bs[128 * 32];
  f32x4 acc[4][4];
#pragma unroll
  for (int i = 0; i < 4; ++i)
#pragma unroll
    for (int j = 0; j < 4; ++j)
#pragma unroll
      for (int r = 0; r < 4; ++r) acc[i][j][r] = 0.f;
  const int m0 = blockIdx.x * 128, n0 = blockIdx.y * 128;
  gemm_core<128, 128>(A, Wot, 512, m0, n0, As, Bs, acc);

  const int lane = threadIdx.x & 63, wave = threadIdx.x >> 6;
  const int wm = wave >> 1, wn = wave & 1, l15 = lane & 15, l4 = lane >> 4;
#pragma unroll
  for (int mi = 0; mi < 4; ++mi)
#pragma unroll
    for (int ni = 0; ni < 4; ++ni) {
      int gcol = n0 + wn * 64 + ni * 16 + l15;
      float bb = bo[gcol];
#pragma unroll
      for (int r = 0; r < 4; ++r) {
        int grow = m0 + wm * 64 + mi * 16 + l4 * 4 + r;
        size_t idx = (size_t)grow * 512 + gcol;
        out[idx] = acc[mi][ni][r] + bb + resid[idx];
      }
    }
}

// ---------------------------------------------------------------------------
extern "C" void kernel_launch(void* const* d_in, const int* in_sizes, int n_in,
                              void* d_out, int out_size, void* d_ws, size_t ws_size,
                              hipStream_t stream)
{
  const float* x     = (const float*)d_in[0];
  const float* gamma = (const float*)d_in[1];
  const float* beta  = (const float*)d_in[2];
  const float* wq    = (const float*)d_in[3];
  const float* bq    = (const float*)d_in[4];
  const float* wk    = (const float*)d_in[5];
  const float* bk    = (const float*)d_in[6];
  const float* wv    = (const float*)d_in[7];
  const float* bv    = (const float*)d_in[8];
  const float* wo    = (const float*)d_in[9];
  const float* bo    = (const float*)d_in[10];
  float* out = (float*)d_out;

  char* ws = (char*)d_ws;
  size_t off = 0;
  auto alloc = [&](size_t bytes) -> char* {
    char* p = ws + off;
    off += (bytes + 255) & ~(size_t)255;
    return p;
  };
  float*  meanv   = (float*)alloc(128 * 4);
  float*  rstdv   = (float*)alloc(128 * 4);
  __bf16* x16     = (__bf16*)alloc(16384ull * 512 * 2);   // 16 MB
  __bf16* wqkvt   = (__bf16*)alloc(1536ull * 512 * 2);    // 1.5 MB
  float*  biasqkv = (float*)alloc(1536 * 4);
  __bf16* wot     = (__bf16*)alloc(512ull * 512 * 2);     // 0.5 MB
  float*  lsum    = (float*)alloc(16384ull * 4);          // 64 KB row sums
  unsigned char* q8  = (unsigned char*)alloc(16384ull * 512);     // 8 MB fp8 Q
  unsigned char* k8  = (unsigned char*)alloc(16384ull * 512);     // 8 MB fp8 K
  unsigned char* vt8 = (unsigned char*)alloc(16384ull * 512);     // 8 MB fp8 V^T
  __bf16* attn    = (__bf16*)alloc(16384ull * 512 * 2);   // 16 MB
  unsigned char* S8 = (unsigned char*)alloc(4ull * 4096 * 4096);  // 64 MB fp8 exp(scores)
  // total ~122 MB

  k_gnstats<<<dim3(128), dim3(256), 0, stream>>>(x, meanv, rstdv);
  k_norm<<<dim3(8192), dim3(256), 0, stream>>>(x, meanv, rstdv, gamma, beta, x16);
  k_prep<<<dim3(4166), dim3(256), 0, stream>>>(wq, bq, wk, bk, wv, bv, wo,
                                               wqkvt, biasqkv, wot, lsum);
  k_gemm_qkv<<<dim3(128, 12), dim3(256), 0, stream>>>(x16, wqkvt, biasqkv, q8, k8, vt8);
  k_gemm_s<<<dim3(32, 32, 4), dim3(256), 0, stream>>>(q8, k8, S8, lsum);
  k_gemm_pv<<<dim3(32, 4, 4), dim3(256), 0, stream>>>(S8, vt8, lsum, attn);
  k_gemm_out<<<dim3(128, 4), dim3(256), 0, stream>>>(attn, wot, bo, x, out);
}

// Round 7
// 318.822 us; speedup vs baseline: 1.2577x; 1.2577x over previous
//
#include <hip/hip_runtime.h>

// ---------------------------------------------------------------------------
// VAEAttention: GroupNorm(32) -> q,k,v 1x1 conv -> full spatial attention
// (N=4096 tokens, d=512) -> out proj -> +residual.   B=4, H=W=64, C=512.
// R14: mx32-scores arc closed (R10/R13: compiler pins ~144 VGPR -> 11% occ).
// k_gemm_s reverted to R12-exact (fp8 16x16 dbuf core + R9 epilogue; 86us,
// 84 VGPR, ~800 TF = the 128^2 2-barrier structure ceiling).  This round's
// single change: the bf16 core (qkv / out projections) gets the same
// 2-phase prefetch double-buffer (R12's +7% transformation).
// PV keeps the mx32_db core (its proven best).
// ---------------------------------------------------------------------------

typedef __bf16 bf16x8 __attribute__((ext_vector_type(8)));
typedef __bf16 bf16x4 __attribute__((ext_vector_type(4)));
typedef float  f32x4  __attribute__((ext_vector_type(4)));
typedef float  f32x16 __attribute__((ext_vector_type(16)));
typedef int    i32x8  __attribute__((ext_vector_type(8)));

#define GLDS(gp, lp) __builtin_amdgcn_global_load_lds( \
    (const __attribute__((address_space(1))) void*)(gp), \
    (__attribute__((address_space(3))) void*)(lp), 16, 0, 0)

// fp32 -> fp8 e4m3 (OCP on gfx950), RNE via HW cvt. Low byte of packed pair.
__device__ __forceinline__ unsigned char f2fp8(float x) {
  int p = __builtin_amdgcn_cvt_pk_fp8_f32(x, 0.f, 0, false);
  return (unsigned char)(p & 0xff);
}

// ---------------------------------------------------------------------------
// GroupNorm stats: one block per (b,g).  64*64 pixels * 16 channels = 65536.
// ---------------------------------------------------------------------------
__global__ __launch_bounds__(256) void k_gnstats(
    const float* __restrict__ x, float* __restrict__ meanv, float* __restrict__ rstdv)
{
  const int bg = blockIdx.x;            // b*32+g
  const int b = bg >> 5, g = bg & 31;
  const float* base = x + (size_t)b * 2097152 + g * 16;
  float s = 0.f, ss = 0.f;
  for (int p = threadIdx.x; p < 4096; p += 256) {
    const float4* rp = (const float4*)(base + (size_t)p * 512);
#pragma unroll
    for (int j = 0; j < 4; ++j) {
      float4 t = rp[j];
      s  += t.x + t.y + t.z + t.w;
      ss += t.x * t.x + t.y * t.y + t.z * t.z + t.w * t.w;
    }
  }
  for (int off = 32; off; off >>= 1) { s += __shfl_xor(s, off, 64); ss += __shfl_xor(ss, off, 64); }
  __shared__ float rs[4], rss[4];
  if ((threadIdx.x & 63) == 0) { rs[threadIdx.x >> 6] = s; rss[threadIdx.x >> 6] = ss; }
  __syncthreads();
  if (threadIdx.x == 0) {
    float S = rs[0] + rs[1] + rs[2] + rs[3];
    float SS = rss[0] + rss[1] + rss[2] + rss[3];
    float m = S * (1.f / 65536.f);
    float var = SS * (1.f / 65536.f) - m * m;
    meanv[bg] = m;
    rstdv[bg] = rsqrtf(var + 1e-6f);
  }
}

// ---------------------------------------------------------------------------
// Normalize + affine + cast to bf16.  8.4M elements, float4 per thread.
// ---------------------------------------------------------------------------
__global__ __launch_bounds__(256) void k_norm(
    const float* __restrict__ x, const float* __restrict__ meanv,
    const float* __restrict__ rstdv, const float* __restrict__ gamma,
    const float* __restrict__ beta, __bf16* __restrict__ x16)
{
  size_t i4 = (size_t)blockIdx.x * 256 + threadIdx.x;  // 0..2097151
  size_t i = i4 * 4;
  int c = (int)(i & 511);
  int bg = (int)(i >> 21) * 32 + (c >> 4);
  float m = meanv[bg], r = rstdv[bg];
  float4 xv = *(const float4*)(x + i);
  float4 gv = *(const float4*)(gamma + c);
  float4 bv = *(const float4*)(beta + c);
  bf16x4 o;
  o[0] = (__bf16)((xv.x - m) * r * gv.x + bv.x);
  o[1] = (__bf16)((xv.y - m) * r * gv.y + bv.y);
  o[2] = (__bf16)((xv.z - m) * r * gv.z + bv.z);
  o[3] = (__bf16)((xv.w - m) * r * gv.w + bv.w);
  *(bf16x4*)(x16 + i) = o;
}

// ---------------------------------------------------------------------------
// Weight prep: Bt layouts (row = output dim, contiguous K).
// wqkvt[1536][512] (wq scaled by 1/sqrt(512)), biasqkv[1536], wot[512][512].
// Also zeroes the row-sum buffer l[16384] (tail of index range).
// ---------------------------------------------------------------------------
__global__ __launch_bounds__(256) void k_prep(
    const float* __restrict__ wq, const float* __restrict__ bq,
    const float* __restrict__ wk, const float* __restrict__ bk,
    const float* __restrict__ wv, const float* __restrict__ bv,
    const float* __restrict__ wo,
    __bf16* __restrict__ wqkvt, float* __restrict__ biasqkv, __bf16* __restrict__ wot,
    float* __restrict__ lsum)
{
  const float sc = 0.04419417382415922f;  // 1/sqrt(512)
  int idx = blockIdx.x * 256 + threadIdx.x;
  if (idx < 786432) {
    int d = idx >> 9, c = idx & 511;
    float v;
    if (d < 512)       v = wq[c * 512 + d] * sc;
    else if (d < 1024) v = wk[c * 512 + d - 512];
    else               v = wv[c * 512 + d - 1024];
    wqkvt[idx] = (__bf16)v;
  } else if (idx < 786432 + 262144) {
    int j = idx - 786432;
    int d = j >> 9, c = j & 511;
    wot[j] = (__bf16)wo[c * 512 + d];
  } else if (idx < 786432 + 262144 + 1536) {
    int d = idx - 786432 - 262144;
    float v = (d < 512) ? bq[d] * sc : (d < 1024 ? bk[d - 512] : bv[d - 1024]);
    biasqkv[d] = v;
  } else if (idx < 786432 + 262144 + 1536 + 16384) {
    lsum[idx - 786432 - 262144 - 1536] = 0.f;
  }
}

// ---------------------------------------------------------------------------
// GEMM core (bf16, XOR-swizzled LDS, 2-phase double-buffer):
// prologue stages tile 0; per tile: STAGE(t+1) -> ds_read+MFMA(t) -> ONE
// barrier (same proven transformation as the R12 fp8 core).
// ---------------------------------------------------------------------------
template <int BM, int BN>
__device__ __forceinline__ void gemm_core_db(
    const __bf16* __restrict__ A, const __bf16* __restrict__ Bt, int K,
    int m0, int n0, __bf16* smem, f32x4 (&acc)[BM / 32][BN / 32])
{
  constexpr int FM = BM / 32, FN = BN / 32;
  constexpr int ASZ = BM * 32;          // elements per A tile (BM x 32)
  constexpr int BSZ = BN * 32;
  constexpr int BUF = ASZ + BSZ;
  const int tid = threadIdx.x;
  const int lane = tid & 63;
  const int wave = tid >> 6;
  const int wm = wave >> 1, wn = wave & 1;
  const int l15 = lane & 15, l4 = lane >> 4;
  const int sw = (l15 >> 1) & 3;            // read-side chunk swizzle
  const int nt = K >> 5;

  auto stage = [&](int b, int kt) {
    __bf16* As_ = smem + b * BUF;
    __bf16* Bs_ = As_ + ASZ;
#pragma unroll
    for (int i = 0; i < BM / 64; ++i) {
      int ci = i * 256 + tid;
      int row = ci >> 2, kc = ci & 3;
      int kcs = kc ^ ((row >> 1) & 3);       // swizzled source chunk
      GLDS(A + (size_t)(m0 + row) * K + kt + kcs * 8, As_ + i * 2048 + wave * 512);
    }
#pragma unroll
    for (int i = 0; i < BN / 64; ++i) {
      int ci = i * 256 + tid;
      int row = ci >> 2, kc = ci & 3;
      int kcs = kc ^ ((row >> 1) & 3);
      GLDS(Bt + (size_t)(n0 + row) * K + kt + kcs * 8, Bs_ + i * 2048 + wave * 512);
    }
  };

  stage(0, 0);
  __syncthreads();                       // tile 0 valid
  for (int t = 0; t < nt; ++t) {
    if (t + 1 < nt) stage((t + 1) & 1, (t + 1) * 32);
    const __bf16* As = smem + (t & 1) * BUF;
    const __bf16* Bs = As + ASZ;
    bf16x8 af[FM], bfr[FN];
#pragma unroll
    for (int mi = 0; mi < FM; ++mi)
      af[mi] = *(const bf16x8*)&As[(wm * (BM / 2) + mi * 16 + l15) * 32 + (l4 ^ sw) * 8];
#pragma unroll
    for (int ni = 0; ni < FN; ++ni)
      bfr[ni] = *(const bf16x8*)&Bs[(wn * (BN / 2) + ni * 16 + l15) * 32 + (l4 ^ sw) * 8];
#pragma unroll
    for (int mi = 0; mi < FM; ++mi)
#pragma unroll
      for (int ni = 0; ni < FN; ++ni)
        acc[mi][ni] = __builtin_amdgcn_mfma_f32_16x16x32_bf16(af[mi], bfr[ni], acc[mi][ni], 0, 0, 0);
    __syncthreads();  // t+1 loads drained; buf[t&1] reads done before overwrite
  }
}

// ---------------------------------------------------------------------------
// GEMM core (fp8 x fp8, BK=64, XOR-swizzled, 2-phase double-buffer):
// R12-verified (86us on k_gemm_s, VGPR 84).
// ---------------------------------------------------------------------------
template <int BM, int BN>
__device__ __forceinline__ void gemm_core_fp8_db(
    const unsigned char* __restrict__ A, const unsigned char* __restrict__ Bt,
    int K, int m0, int n0, unsigned char* smem,
    f32x4 (&acc)[BM / 32][BN / 32])
{
  constexpr int FM = BM / 32, FN = BN / 32;
  constexpr int ASZ = (BM / 64) * 4096;   // A tile bytes (BM x 64)
  constexpr int BSZ = (BN / 64) * 4096;
  constexpr int BUF = ASZ + BSZ;
  const int tid = threadIdx.x;
  const int lane = tid & 63;
  const int wave = tid >> 6;
  const int wm = wave >> 1, wn = wave & 1;
  const int l15 = lane & 15, l4 = lane >> 4;
  const int sw = (l15 >> 1) & 3;
  const int h8 = (l4 & 1) * 8;      // 8B half within a 16B chunk
  const int nt = K >> 6;

  auto stage = [&](int b, int kt) {
    unsigned char* As_ = smem + b * BUF;
    unsigned char* Bs_ = As_ + ASZ;
#pragma unroll
    for (int i = 0; i < BM / 64; ++i) {
      int ci = i * 256 + tid;
      int row = ci >> 2, kc = ci & 3;
      int kcs = (kc ^ ((row >> 1) & 3)) * 16;  // swizzled 16B source chunk
      GLDS(A + (size_t)(m0 + row) * K + kt + kcs, As_ + i * 4096 + wave * 1024);
    }
#pragma unroll
    for (int i = 0; i < BN / 64; ++i) {
      int ci = i * 256 + tid;
      int row = ci >> 2, kc = ci & 3;
      int kcs = (kc ^ ((row >> 1) & 3)) * 16;
      GLDS(Bt + (size_t)(n0 + row) * K + kt + kcs, Bs_ + i * 4096 + wave * 1024);
    }
  };

  stage(0, 0);
  __syncthreads();                       // tile 0 valid
  for (int t = 0; t < nt; ++t) {
    if (t + 1 < nt) stage((t + 1) & 1, (t + 1) * 64);
    const unsigned char* As = smem + (t & 1) * BUF;
    const unsigned char* Bs = As + ASZ;
    long long af[FM][2], bfr[FN][2];
#pragma unroll
    for (int mi = 0; mi < FM; ++mi) {
      int row = wm * (BM / 2) + mi * 16 + l15;
#pragma unroll
      for (int j = 0; j < 2; ++j) {
        int G = j * 2 + (l4 >> 1);           // global 16B-chunk index
        af[mi][j] = *(const long long*)&As[row * 64 + ((G ^ sw) << 4) + h8];
      }
    }
#pragma unroll
    for (int ni = 0; ni < FN; ++ni) {
      int row = wn * (BN / 2) + ni * 16 + l15;
#pragma unroll
      for (int j = 0; j < 2; ++j) {
        int G = j * 2 + (l4 >> 1);
        bfr[ni][j] = *(const long long*)&Bs[row * 64 + ((G ^ sw) << 4) + h8];
      }
    }
#pragma unroll
    for (int mi = 0; mi < FM; ++mi)
#pragma unroll
      for (int ni = 0; ni < FN; ++ni) {
        f32x4 c = acc[mi][ni];
        c = __builtin_amdgcn_mfma_f32_16x16x32_fp8_fp8(af[mi][0], bfr[ni][0], c, 0, 0, 0);
        c = __builtin_amdgcn_mfma_f32_16x16x32_fp8_fp8(af[mi][1], bfr[ni][1], c, 0, 0, 0);
        acc[mi][ni] = c;
      }
    __syncthreads();  // t+1 loads drained; buf[t&1] reads done before overwrite
  }
}

// ---------------------------------------------------------------------------
// GEMM core (MX fp8, 32x32x64, scale=1.0, 2-phase double-buffer): PV only.
// (k_gemm_s context pins this core at ~144 VGPR -> 11% occ; R10/R13.)
// A-operand: lane l holds row (l&31), k-bytes [ (l>>5)*32 , +32 ).
// C/D (m74/m101): col = lane&31, row = (r&3)+8*(r>>2)+4*(l>>5).
// ---------------------------------------------------------------------------
template <int BM, int BN>
__device__ __forceinline__ void gemm_core_mx32_db(
    const unsigned char* __restrict__ A, const unsigned char* __restrict__ Bt,
    int K, int m0, int n0, unsigned char* smem,
    f32x16 (&acc)[BM / 64][BN / 64])
{
  constexpr int FM = BM / 64, FN = BN / 64;
  constexpr int ASZ = (BM / 64) * 4096;
  constexpr int BSZ = (BN / 64) * 4096;
  constexpr int BUF = ASZ + BSZ;
  const int tid = threadIdx.x;
  const int lane = tid & 63;
  const int wave = tid >> 6;
  const int wm = wave >> 1, wn = wave & 1;
  const int l31 = lane & 31, h = lane >> 5;   // h: k-block of 32 bytes
  const int nt = K >> 6;

  auto stage = [&](int b, int kt) {
    unsigned char* As_ = smem + b * BUF;
    unsigned char* Bs_ = As_ + ASZ;
#pragma unroll
    for (int i = 0; i < BM / 64; ++i) {
      int ci = i * 256 + tid;
      int row = ci >> 2, kc = ci & 3;
      int kcs = (kc ^ ((row >> 1) & 3)) * 16;
      GLDS(A + (size_t)(m0 + row) * K + kt + kcs, As_ + i * 4096 + wave * 1024);
    }
#pragma unroll
    for (int i = 0; i < BN / 64; ++i) {
      int ci = i * 256 + tid;
      int row = ci >> 2, kc = ci & 3;
      int kcs = (kc ^ ((row >> 1) & 3)) * 16;
      GLDS(Bt + (size_t)(n0 + row) * K + kt + kcs, Bs_ + i * 4096 + wave * 1024);
    }
  };

  stage(0, 0);
  __syncthreads();
  for (int t = 0; t < nt; ++t) {
    if (t + 1 < nt) stage((t + 1) & 1, (t + 1) * 64);
    const unsigned char* As = smem + (t & 1) * BUF;
    const unsigned char* Bs = As + ASZ;
    i32x8 af[FM], bfr[FN];
#pragma unroll
    for (int mi = 0; mi < FM; ++mi) {
      int row = wm * (BM / 2) + mi * 32 + l31;
      int s = (row >> 1) & 3;
      int c0 = (2 * h) ^ s, c1 = (2 * h + 1) ^ s;   // two 16B chunks = 32B of k
      uint4 u0 = *(const uint4*)&As[row * 64 + c0 * 16];
      uint4 u1 = *(const uint4*)&As[row * 64 + c1 * 16];
      af[mi][0] = (int)u0.x; af[mi][1] = (int)u0.y; af[mi][2] = (int)u0.z; af[mi][3] = (int)u0.w;
      af[mi][4] = (int)u1.x; af[mi][5] = (int)u1.y; af[mi][6] = (int)u1.z; af[mi][7] = (int)u1.w;
    }
#pragma unroll
    for (int ni = 0; ni < FN; ++ni) {
      int row = wn * (BN / 2) + ni * 32 + l31;
      int s = (row >> 1) & 3;
      int c0 = (2 * h) ^ s, c1 = (2 * h + 1) ^ s;
      uint4 u0 = *(const uint4*)&Bs[row * 64 + c0 * 16];
      uint4 u1 = *(const uint4*)&Bs[row * 64 + c1 * 16];
      bfr[ni][0] = (int)u0.x; bfr[ni][1] = (int)u0.y; bfr[ni][2] = (int)u0.z; bfr[ni][3] = (int)u0.w;
      bfr[ni][4] = (int)u1.x; bfr[ni][5] = (int)u1.y; bfr[ni][6] = (int)u1.z; bfr[ni][7] = (int)u1.w;
    }
#pragma unroll
    for (int mi = 0; mi < FM; ++mi)
#pragma unroll
      for (int ni = 0; ni < FN; ++ni)
        acc[mi][ni] = __builtin_amdgcn_mfma_scale_f32_32x32x64_f8f6f4(
            af[mi], bfr[ni], acc[mi][ni],
            0, 0,                       // cbsz/blgp = fp8 e4m3
            0, 0x7f7f7f7f,              // scale_a: e8m0 = 1.0
            0, 0x7f7f7f7f);             // scale_b: e8m0 = 1.0
    __syncthreads();
  }
}

// fp8 16x16 C/D layout (measured m89/m91): col = lane&15, row = (lane>>4)*4 + reg.

// ---------------------------------------------------------------------------
// QKV GEMM: X[16384][512] @ Wqkv^T.  q,k stored fp8 row-major (scores GEMM
// is fp8); v transposed + fp8 (vt8[b][c][n]) for the fp8 PV GEMM.  Bias fused.
// ---------------------------------------------------------------------------
__global__ __launch_bounds__(256) void k_gemm_qkv(
    const __bf16* __restrict__ X, const __bf16* __restrict__ Wt,
    const float* __restrict__ bias, unsigned char* __restrict__ q8,
    unsigned char* __restrict__ k8, unsigned char* __restrict__ vt8)
{
  __shared__ __align__(16) __bf16 smem[2 * (128 * 32 + 128 * 32)];  // 32 KB dbuf
  f32x4 acc[4][4];
#pragma unroll
  for (int i = 0; i < 4; ++i)
#pragma unroll
    for (int j = 0; j < 4; ++j)
#pragma unroll
      for (int r = 0; r < 4; ++r) acc[i][j][r] = 0.f;
  const int m0 = blockIdx.x * 128, n0 = blockIdx.y * 128;
  gemm_core_db<128, 128>(X, Wt, 512, m0, n0, smem, acc);

  const int lane = threadIdx.x & 63, wave = threadIdx.x >> 6;
  const int wm = wave >> 1, wn = wave & 1, l15 = lane & 15, l4 = lane >> 4;
#pragma unroll
  for (int mi = 0; mi < 4; ++mi) {
#pragma unroll
    for (int ni = 0; ni < 4; ++ni) {
      int gcol = n0 + wn * 64 + ni * 16 + l15;
      float bb = bias[gcol];
#pragma unroll
      for (int r = 0; r < 4; ++r) {
        int grow = m0 + wm * 64 + mi * 16 + l4 * 4 + r;
        float val = acc[mi][ni][r] + bb;
        int b = grow >> 12, n = grow & 4095;
        if (gcol < 512)
          q8[(size_t)grow * 512 + gcol] = f2fp8(val);
        else if (gcol < 1024)
          k8[(size_t)grow * 512 + (gcol - 512)] = f2fp8(val);
        else
          vt8[((size_t)b * 512 + (gcol - 1024)) * 4096 + n] = f2fp8(val);
      }
    }
  }
}

// ---------------------------------------------------------------------------
// Scores GEMM (fp8 x fp8, BK=64, 2-phase dbuf) + max-free softmax numerator,
// batched over z: P[b][n][m] = exp(q.k) stored fp8 e4m3; lsum fp32 row sums.
// Epilogue: exact R9 (exp+rowsum in regs, 4-pass LDS transpose, 16B stores).
// (R12-exact kernel: 86us, 84 VGPR, 28.5% occ.)
// ---------------------------------------------------------------------------
__global__ __launch_bounds__(256) void k_gemm_s(
    const unsigned char* __restrict__ qall, const unsigned char* __restrict__ kall,
    unsigned char* __restrict__ S8all, float* __restrict__ lsum)
{
  __shared__ __align__(16) unsigned char smem[32768];  // 2 x (8KB As + 8KB Bs)
  f32x4 acc[4][4];
#pragma unroll
  for (int i = 0; i < 4; ++i)
#pragma unroll
    for (int j = 0; j < 4; ++j)
#pragma unroll
      for (int r = 0; r < 4; ++r) acc[i][j][r] = 0.f;

  // supertile swizzle: 1024 blocks/batch -> 16 groups of 64 (8x8)
  const int b = blockIdx.z;
  const int flat = blockIdx.x + (blockIdx.y << 5);
  const int gx = flat & 7, gy = (flat >> 3) & 7, grp = flat >> 6;
  const int bx = (grp & 3) * 8 + gx, by = (grp >> 2) * 8 + gy;
  const int m0 = bx * 128, n0 = by * 128;

  const unsigned char* q = qall + (size_t)b * 4096 * 512;
  const unsigned char* k = kall + (size_t)b * 4096 * 512;
  unsigned char* S8 = S8all + (size_t)b * 4096 * 4096;
  gemm_core_fp8_db<128, 128>(q, k, 512, m0, n0, smem, acc);

  const int lane = threadIdx.x & 63, wave = threadIdx.x >> 6;
  const int wm = wave >> 1, wn = wave & 1, l15 = lane & 15, l4 = lane >> 4;

  // exp in place + fp32 row-sum atomics (pre-fp8-rounding; unbiased)
#pragma unroll
  for (int mi = 0; mi < 4; ++mi) {
    float rsum[4] = {0.f, 0.f, 0.f, 0.f};
#pragma unroll
    for (int ni = 0; ni < 4; ++ni)
#pragma unroll
      for (int r = 0; r < 4; ++r) {
        float p = __expf(acc[mi][ni][r]);
        acc[mi][ni][r] = p;
        rsum[r] += p;
      }
#pragma unroll
    for (int r = 0; r < 4; ++r) {
#pragma unroll
      for (int off = 1; off < 16; off <<= 1) rsum[r] += __shfl_xor(rsum[r], off, 64);
      if (l15 == 0) {
        int grow = m0 + wm * 64 + mi * 16 + l4 * 4 + r;
        atomicAdd(&lsum[b * 4096 + grow], rsum[r]);
      }
    }
  }

  // 4-pass transpose to fp8: pass p covers local rows [32p, 32p+32)
  unsigned char* t8 = smem;  // 32 x (stride 144) = 4.6 KB
#pragma unroll
  for (int p = 0; p < 4; ++p) {
    __syncthreads();
    if (wm == (p >> 1)) {
      const int mibase = (p & 1) * 2;
#pragma unroll
      for (int mm = 0; mm < 2; ++mm)
#pragma unroll
        for (int ni = 0; ni < 4; ++ni) {
          int lcol = wn * 64 + ni * 16 + l15;
#pragma unroll
          for (int r = 0; r < 4; ++r) {
            int lrow = mm * 16 + l4 * 4 + r;  // 0..31
            t8[lrow * 144 + lcol] = f2fp8(acc[mibase + mm][ni][r]);
          }
        }
    }
    __syncthreads();
    // store 32 rows x 128 B: 256 chunks of 16B, 1 per thread
    int crow = threadIdx.x >> 3, ccol = (threadIdx.x & 7) * 16;
    uint4 v = *(const uint4*)&t8[crow * 144 + ccol];
    *(uint4*)&S8[(size_t)(m0 + p * 32 + crow) * 4096 + n0 + ccol] = v;
  }
}

// ---------------------------------------------------------------------------
// PV GEMM (MX fp8 32x32x64, BK=64, 2-phase dbuf), batched over z:
// O[b,n,c] = (sum_m P[b,n,m] * vt[b,c,m]) / l[b,n].
// ---------------------------------------------------------------------------
__global__ __launch_bounds__(256) void k_gemm_pv(
    const unsigned char* __restrict__ S8all, const unsigned char* __restrict__ vt8all,
    const float* __restrict__ lsum, __bf16* __restrict__ attn)
{
  __shared__ __align__(16) unsigned char smem[32768];  // 2 x (8KB As + 8KB Bs)
  f32x16 acc[2][2];
#pragma unroll
  for (int i = 0; i < 2; ++i)
#pragma unroll
    for (int j = 0; j < 2; ++j)
#pragma unroll
      for (int r = 0; r < 16; ++r) acc[i][j][r] = 0.f;
  const int b = blockIdx.z;
  const unsigned char* P = S8all + (size_t)b * 4096 * 4096;
  const unsigned char* V = vt8all + (size_t)b * 512 * 4096;
  __bf16* O = attn + (size_t)b * 4096 * 512;
  const int m0 = blockIdx.x * 128, n0 = blockIdx.y * 128;
  gemm_core_mx32_db<128, 128>(P, V, 4096, m0, n0, smem, acc);

  const int lane = threadIdx.x & 63, wave = threadIdx.x >> 6;
  const int wm = wave >> 1, wn = wave & 1, l31 = lane & 31, h = lane >> 5;
#pragma unroll
  for (int mi = 0; mi < 2; ++mi)
#pragma unroll
    for (int ni = 0; ni < 2; ++ni) {
      int gcol = n0 + wn * 64 + ni * 32 + l31;
#pragma unroll
      for (int r = 0; r < 16; ++r) {
        int grow = m0 + wm * 64 + mi * 32 + (r & 3) + 8 * (r >> 2) + 4 * h;
        float inv = 1.f / lsum[b * 4096 + grow];
        O[(size_t)grow * 512 + gcol] = (__bf16)(acc[mi][ni][r] * inv);
      }
    }
}

// ---------------------------------------------------------------------------
// Output projection + bias + residual, fp32 store to d_out.
// ---------------------------------------------------------------------------
__global__ __launch_bounds__(256) void k_gemm_out(
    const __bf16* __restrict__ A, const __bf16* __restrict__ Wot,
    const float* __restrict__ bo, const float* __restrict__ resid, float* __restrict__ out)
{
  __shared__ __align__(16) __bf16 smem[2 * (128 * 32 + 128 * 32)];  // 32 KB dbuf
  f32x4 acc[4][4];
#pragma unroll
  for (int i = 0; i < 4; ++i)
#pragma unroll
    for (int j = 0; j < 4; ++j)
#pragma unroll
      for (int r = 0; r < 4; ++r) acc[i][j][r] = 0.f;
  const int m0 = blockIdx.x * 128, n0 = blockIdx.y * 128;
  gemm_core_db<128, 128>(A, Wot, 512, m0, n0, smem, acc);

  const int lane = threadIdx.x & 63, wave = threadIdx.x >> 6;
  const int wm = wave >> 1, wn = wave & 1, l15 = lane & 15, l4 = lane >> 4;
#pragma unroll
  for (int mi = 0; mi < 4; ++mi)
#pragma unroll
    for (int ni = 0; ni < 4; ++ni) {
      int gcol = n0 + wn * 64 + ni * 16 + l15;
      float bb = bo[gcol];
#pragma unroll
      for (int r = 0; r < 4; ++r) {
        int grow = m0 + wm * 64 + mi * 16 + l4 * 4 + r;
        size_t idx = (size_t)grow * 512 + gcol;
        out[idx] = acc[mi][ni][r] + bb + resid[idx];
      }
    }
}

// ---------------------------------------------------------------------------
extern "C" void kernel_launch(void* const* d_in, const int* in_sizes, int n_in,
                              void* d_out, int out_size, void* d_ws, size_t ws_size,
                              hipStream_t stream)
{
  const float* x     = (const float*)d_in[0];
  const float* gamma = (const float*)d_in[1];
  const float* beta  = (const float*)d_in[2];
  const float* wq    = (const float*)d_in[3];
  const float* bq    = (const float*)d_in[4];
  const float* wk    = (const float*)d_in[5];
  const float* bk    = (const float*)d_in[6];
  const float* wv    = (const float*)d_in[7];
  const float* bv    = (const float*)d_in[8];
  const float* wo    = (const float*)d_in[9];
  const float* bo    = (const float*)d_in[10];
  float* out = (float*)d_out;

  char* ws = (char*)d_ws;
  size_t off = 0;
  auto alloc = [&](size_t bytes) -> char* {
    char* p = ws + off;
    off += (bytes + 255) & ~(size_t)255;
    return p;
  };
  float*  meanv   = (float*)alloc(128 * 4);
  float*  rstdv   = (float*)alloc(128 * 4);
  __bf16* x16     = (__bf16*)alloc(16384ull * 512 * 2);   // 16 MB
  __bf16* wqkvt   = (__bf16*)alloc(1536ull * 512 * 2);    // 1.5 MB
  float*  biasqkv = (float*)alloc(1536 * 4);
  __bf16* wot     = (__bf16*)alloc(512ull * 512 * 2);     // 0.5 MB
  float*  lsum    = (float*)alloc(16384ull * 4);          // 64 KB row sums
  unsigned char* q8  = (unsigned char*)alloc(16384ull * 512);     // 8 MB fp8 Q
  unsigned char* k8  = (unsigned char*)alloc(16384ull * 512);     // 8 MB fp8 K
  unsigned char* vt8 = (unsigned char*)alloc(16384ull * 512);     // 8 MB fp8 V^T
  __bf16* attn    = (__bf16*)alloc(16384ull * 512 * 2);   // 16 MB
  unsigned char* S8 = (unsigned char*)alloc(4ull * 4096 * 4096);  // 64 MB fp8 exp(scores)
  // total ~122 MB

  k_gnstats<<<dim3(128), dim3(256), 0, stream>>>(x, meanv, rstdv);
  k_norm<<<dim3(8192), dim3(256), 0, stream>>>(x, meanv, rstdv, gamma, beta, x16);
  k_prep<<<dim3(4166), dim3(256), 0, stream>>>(wq, bq, wk, bk, wv, bv, wo,
                                               wqkvt, biasqkv, wot, lsum);
  k_gemm_qkv<<<dim3(128, 12), dim3(256), 0, stream>>>(x16, wqkvt, biasqkv, q8, k8, vt8);
  k_gemm_s<<<dim3(32, 32, 4), dim3(256), 0, stream>>>(q8, k8, S8, lsum);
  k_gemm_pv<<<dim3(32, 4, 4), dim3(256), 0, stream>>>(S8, vt8, lsum, attn);
  k_gemm_out<<<dim3(128, 4), dim3(256), 0, stream>>>(attn, wot, bo, x, out);
}

// Round 8
// 308.914 us; speedup vs baseline: 1.2981x; 1.0321x over previous
//
#include <hip/hip_runtime.h>

// ---------------------------------------------------------------------------
// VAEAttention: GroupNorm(32) -> q,k,v 1x1 conv -> full spatial attention
// (N=4096 tokens, d=512) -> out proj -> +residual.   B=4, H=W=64, C=512.
// R15: epilogue trims.  (1) k_gemm_s: 1-pass LDS transpose (128x144 tile in
// the 32KB dbuf smem; 2 barriers instead of 8).  (2) k_gemm_qkv: all outputs
// staged in LDS and stored as coalesced 16B chunks (q/k direct, v transposed)
// -- kills the ~4x write amplification of the scattered byte stores.
// Cores unchanged from R14 (fp8 16x16 dbuf scores @805TF, mx32 PV, bf16 dbuf
// projections).
// ---------------------------------------------------------------------------

typedef __bf16 bf16x8 __attribute__((ext_vector_type(8)));
typedef __bf16 bf16x4 __attribute__((ext_vector_type(4)));
typedef float  f32x4  __attribute__((ext_vector_type(4)));
typedef float  f32x16 __attribute__((ext_vector_type(16)));
typedef int    i32x8  __attribute__((ext_vector_type(8)));

#define GLDS(gp, lp) __builtin_amdgcn_global_load_lds( \
    (const __attribute__((address_space(1))) void*)(gp), \
    (__attribute__((address_space(3))) void*)(lp), 16, 0, 0)

// fp32 -> fp8 e4m3 (OCP on gfx950), RNE via HW cvt. Low byte of packed pair.
__device__ __forceinline__ unsigned char f2fp8(float x) {
  int p = __builtin_amdgcn_cvt_pk_fp8_f32(x, 0.f, 0, false);
  return (unsigned char)(p & 0xff);
}

// ---------------------------------------------------------------------------
// GroupNorm stats: one block per (b,g).  64*64 pixels * 16 channels = 65536.
// ---------------------------------------------------------------------------
__global__ __launch_bounds__(256) void k_gnstats(
    const float* __restrict__ x, float* __restrict__ meanv, float* __restrict__ rstdv)
{
  const int bg = blockIdx.x;            // b*32+g
  const int b = bg >> 5, g = bg & 31;
  const float* base = x + (size_t)b * 2097152 + g * 16;
  float s = 0.f, ss = 0.f;
  for (int p = threadIdx.x; p < 4096; p += 256) {
    const float4* rp = (const float4*)(base + (size_t)p * 512);
#pragma unroll
    for (int j = 0; j < 4; ++j) {
      float4 t = rp[j];
      s  += t.x + t.y + t.z + t.w;
      ss += t.x * t.x + t.y * t.y + t.z * t.z + t.w * t.w;
    }
  }
  for (int off = 32; off; off >>= 1) { s += __shfl_xor(s, off, 64); ss += __shfl_xor(ss, off, 64); }
  __shared__ float rs[4], rss[4];
  if ((threadIdx.x & 63) == 0) { rs[threadIdx.x >> 6] = s; rss[threadIdx.x >> 6] = ss; }
  __syncthreads();
  if (threadIdx.x == 0) {
    float S = rs[0] + rs[1] + rs[2] + rs[3];
    float SS = rss[0] + rss[1] + rss[2] + rss[3];
    float m = S * (1.f / 65536.f);
    float var = SS * (1.f / 65536.f) - m * m;
    meanv[bg] = m;
    rstdv[bg] = rsqrtf(var + 1e-6f);
  }
}

// ---------------------------------------------------------------------------
// Normalize + affine + cast to bf16.  8.4M elements, float4 per thread.
// ---------------------------------------------------------------------------
__global__ __launch_bounds__(256) void k_norm(
    const float* __restrict__ x, const float* __restrict__ meanv,
    const float* __restrict__ rstdv, const float* __restrict__ gamma,
    const float* __restrict__ beta, __bf16* __restrict__ x16)
{
  size_t i4 = (size_t)blockIdx.x * 256 + threadIdx.x;  // 0..2097151
  size_t i = i4 * 4;
  int c = (int)(i & 511);
  int bg = (int)(i >> 21) * 32 + (c >> 4);
  float m = meanv[bg], r = rstdv[bg];
  float4 xv = *(const float4*)(x + i);
  float4 gv = *(const float4*)(gamma + c);
  float4 bv = *(const float4*)(beta + c);
  bf16x4 o;
  o[0] = (__bf16)((xv.x - m) * r * gv.x + bv.x);
  o[1] = (__bf16)((xv.y - m) * r * gv.y + bv.y);
  o[2] = (__bf16)((xv.z - m) * r * gv.z + bv.z);
  o[3] = (__bf16)((xv.w - m) * r * gv.w + bv.w);
  *(bf16x4*)(x16 + i) = o;
}

// ---------------------------------------------------------------------------
// Weight prep: Bt layouts (row = output dim, contiguous K).
// wqkvt[1536][512] (wq scaled by 1/sqrt(512)), biasqkv[1536], wot[512][512].
// Also zeroes the row-sum buffer l[16384] (tail of index range).
// ---------------------------------------------------------------------------
__global__ __launch_bounds__(256) void k_prep(
    const float* __restrict__ wq, const float* __restrict__ bq,
    const float* __restrict__ wk, const float* __restrict__ bk,
    const float* __restrict__ wv, const float* __restrict__ bv,
    const float* __restrict__ wo,
    __bf16* __restrict__ wqkvt, float* __restrict__ biasqkv, __bf16* __restrict__ wot,
    float* __restrict__ lsum)
{
  const float sc = 0.04419417382415922f;  // 1/sqrt(512)
  int idx = blockIdx.x * 256 + threadIdx.x;
  if (idx < 786432) {
    int d = idx >> 9, c = idx & 511;
    float v;
    if (d < 512)       v = wq[c * 512 + d] * sc;
    else if (d < 1024) v = wk[c * 512 + d - 512];
    else               v = wv[c * 512 + d - 1024];
    wqkvt[idx] = (__bf16)v;
  } else if (idx < 786432 + 262144) {
    int j = idx - 786432;
    int d = j >> 9, c = j & 511;
    wot[j] = (__bf16)wo[c * 512 + d];
  } else if (idx < 786432 + 262144 + 1536) {
    int d = idx - 786432 - 262144;
    float v = (d < 512) ? bq[d] * sc : (d < 1024 ? bk[d - 512] : bv[d - 1024]);
    biasqkv[d] = v;
  } else if (idx < 786432 + 262144 + 1536 + 16384) {
    lsum[idx - 786432 - 262144 - 1536] = 0.f;
  }
}

// ---------------------------------------------------------------------------
// GEMM core (bf16, XOR-swizzled LDS, 2-phase double-buffer):
// prologue stages tile 0; per tile: STAGE(t+1) -> ds_read+MFMA(t) -> ONE
// barrier (R14-verified).
// ---------------------------------------------------------------------------
template <int BM, int BN>
__device__ __forceinline__ void gemm_core_db(
    const __bf16* __restrict__ A, const __bf16* __restrict__ Bt, int K,
    int m0, int n0, __bf16* smem, f32x4 (&acc)[BM / 32][BN / 32])
{
  constexpr int FM = BM / 32, FN = BN / 32;
  constexpr int ASZ = BM * 32;          // elements per A tile (BM x 32)
  constexpr int BSZ = BN * 32;
  constexpr int BUF = ASZ + BSZ;
  const int tid = threadIdx.x;
  const int lane = tid & 63;
  const int wave = tid >> 6;
  const int wm = wave >> 1, wn = wave & 1;
  const int l15 = lane & 15, l4 = lane >> 4;
  const int sw = (l15 >> 1) & 3;            // read-side chunk swizzle
  const int nt = K >> 5;

  auto stage = [&](int b, int kt) {
    __bf16* As_ = smem + b * BUF;
    __bf16* Bs_ = As_ + ASZ;
#pragma unroll
    for (int i = 0; i < BM / 64; ++i) {
      int ci = i * 256 + tid;
      int row = ci >> 2, kc = ci & 3;
      int kcs = kc ^ ((row >> 1) & 3);       // swizzled source chunk
      GLDS(A + (size_t)(m0 + row) * K + kt + kcs * 8, As_ + i * 2048 + wave * 512);
    }
#pragma unroll
    for (int i = 0; i < BN / 64; ++i) {
      int ci = i * 256 + tid;
      int row = ci >> 2, kc = ci & 3;
      int kcs = kc ^ ((row >> 1) & 3);
      GLDS(Bt + (size_t)(n0 + row) * K + kt + kcs * 8, Bs_ + i * 2048 + wave * 512);
    }
  };

  stage(0, 0);
  __syncthreads();                       // tile 0 valid
  for (int t = 0; t < nt; ++t) {
    if (t + 1 < nt) stage((t + 1) & 1, (t + 1) * 32);
    const __bf16* As = smem + (t & 1) * BUF;
    const __bf16* Bs = As + ASZ;
    bf16x8 af[FM], bfr[FN];
#pragma unroll
    for (int mi = 0; mi < FM; ++mi)
      af[mi] = *(const bf16x8*)&As[(wm * (BM / 2) + mi * 16 + l15) * 32 + (l4 ^ sw) * 8];
#pragma unroll
    for (int ni = 0; ni < FN; ++ni)
      bfr[ni] = *(const bf16x8*)&Bs[(wn * (BN / 2) + ni * 16 + l15) * 32 + (l4 ^ sw) * 8];
#pragma unroll
    for (int mi = 0; mi < FM; ++mi)
#pragma unroll
      for (int ni = 0; ni < FN; ++ni)
        acc[mi][ni] = __builtin_amdgcn_mfma_f32_16x16x32_bf16(af[mi], bfr[ni], acc[mi][ni], 0, 0, 0);
    __syncthreads();  // t+1 loads drained; buf[t&1] reads done before overwrite
  }
}

// ---------------------------------------------------------------------------
// GEMM core (fp8 x fp8, BK=64, XOR-swizzled, 2-phase double-buffer):
// R12/R14-verified (86us on k_gemm_s, VGPR 84).
// ---------------------------------------------------------------------------
template <int BM, int BN>
__device__ __forceinline__ void gemm_core_fp8_db(
    const unsigned char* __restrict__ A, const unsigned char* __restrict__ Bt,
    int K, int m0, int n0, unsigned char* smem,
    f32x4 (&acc)[BM / 32][BN / 32])
{
  constexpr int FM = BM / 32, FN = BN / 32;
  constexpr int ASZ = (BM / 64) * 4096;   // A tile bytes (BM x 64)
  constexpr int BSZ = (BN / 64) * 4096;
  constexpr int BUF = ASZ + BSZ;
  const int tid = threadIdx.x;
  const int lane = tid & 63;
  const int wave = tid >> 6;
  const int wm = wave >> 1, wn = wave & 1;
  const int l15 = lane & 15, l4 = lane >> 4;
  const int sw = (l15 >> 1) & 3;
  const int h8 = (l4 & 1) * 8;      // 8B half within a 16B chunk
  const int nt = K >> 6;

  auto stage = [&](int b, int kt) {
    unsigned char* As_ = smem + b * BUF;
    unsigned char* Bs_ = As_ + ASZ;
#pragma unroll
    for (int i = 0; i < BM / 64; ++i) {
      int ci = i * 256 + tid;
      int row = ci >> 2, kc = ci & 3;
      int kcs = (kc ^ ((row >> 1) & 3)) * 16;  // swizzled 16B source chunk
      GLDS(A + (size_t)(m0 + row) * K + kt + kcs, As_ + i * 4096 + wave * 1024);
    }
#pragma unroll
    for (int i = 0; i < BN / 64; ++i) {
      int ci = i * 256 + tid;
      int row = ci >> 2, kc = ci & 3;
      int kcs = (kc ^ ((row >> 1) & 3)) * 16;
      GLDS(Bt + (size_t)(n0 + row) * K + kt + kcs, Bs_ + i * 4096 + wave * 1024);
    }
  };

  stage(0, 0);
  __syncthreads();                       // tile 0 valid
  for (int t = 0; t < nt; ++t) {
    if (t + 1 < nt) stage((t + 1) & 1, (t + 1) * 64);
    const unsigned char* As = smem + (t & 1) * BUF;
    const unsigned char* Bs = As + ASZ;
    long long af[FM][2], bfr[FN][2];
#pragma unroll
    for (int mi = 0; mi < FM; ++mi) {
      int row = wm * (BM / 2) + mi * 16 + l15;
#pragma unroll
      for (int j = 0; j < 2; ++j) {
        int G = j * 2 + (l4 >> 1);           // global 16B-chunk index
        af[mi][j] = *(const long long*)&As[row * 64 + ((G ^ sw) << 4) + h8];
      }
    }
#pragma unroll
    for (int ni = 0; ni < FN; ++ni) {
      int row = wn * (BN / 2) + ni * 16 + l15;
#pragma unroll
      for (int j = 0; j < 2; ++j) {
        int G = j * 2 + (l4 >> 1);
        bfr[ni][j] = *(const long long*)&Bs[row * 64 + ((G ^ sw) << 4) + h8];
      }
    }
#pragma unroll
    for (int mi = 0; mi < FM; ++mi)
#pragma unroll
      for (int ni = 0; ni < FN; ++ni) {
        f32x4 c = acc[mi][ni];
        c = __builtin_amdgcn_mfma_f32_16x16x32_fp8_fp8(af[mi][0], bfr[ni][0], c, 0, 0, 0);
        c = __builtin_amdgcn_mfma_f32_16x16x32_fp8_fp8(af[mi][1], bfr[ni][1], c, 0, 0, 0);
        acc[mi][ni] = c;
      }
    __syncthreads();  // t+1 loads drained; buf[t&1] reads done before overwrite
  }
}

// ---------------------------------------------------------------------------
// GEMM core (MX fp8, 32x32x64, scale=1.0, 2-phase double-buffer): PV only.
// A-operand: lane l holds row (l&31), k-bytes [ (l>>5)*32 , +32 ).
// C/D (m74/m101): col = lane&31, row = (r&3)+8*(r>>2)+4*(l>>5).
// ---------------------------------------------------------------------------
template <int BM, int BN>
__device__ __forceinline__ void gemm_core_mx32_db(
    const unsigned char* __restrict__ A, const unsigned char* __restrict__ Bt,
    int K, int m0, int n0, unsigned char* smem,
    f32x16 (&acc)[BM / 64][BN / 64])
{
  constexpr int FM = BM / 64, FN = BN / 64;
  constexpr int ASZ = (BM / 64) * 4096;
  constexpr int BSZ = (BN / 64) * 4096;
  constexpr int BUF = ASZ + BSZ;
  const int tid = threadIdx.x;
  const int lane = tid & 63;
  const int wave = tid >> 6;
  const int wm = wave >> 1, wn = wave & 1;
  const int l31 = lane & 31, h = lane >> 5;   // h: k-block of 32 bytes
  const int nt = K >> 6;

  auto stage = [&](int b, int kt) {
    unsigned char* As_ = smem + b * BUF;
    unsigned char* Bs_ = As_ + ASZ;
#pragma unroll
    for (int i = 0; i < BM / 64; ++i) {
      int ci = i * 256 + tid;
      int row = ci >> 2, kc = ci & 3;
      int kcs = (kc ^ ((row >> 1) & 3)) * 16;
      GLDS(A + (size_t)(m0 + row) * K + kt + kcs, As_ + i * 4096 + wave * 1024);
    }
#pragma unroll
    for (int i = 0; i < BN / 64; ++i) {
      int ci = i * 256 + tid;
      int row = ci >> 2, kc = ci & 3;
      int kcs = (kc ^ ((row >> 1) & 3)) * 16;
      GLDS(Bt + (size_t)(n0 + row) * K + kt + kcs, Bs_ + i * 4096 + wave * 1024);
    }
  };

  stage(0, 0);
  __syncthreads();
  for (int t = 0; t < nt; ++t) {
    if (t + 1 < nt) stage((t + 1) & 1, (t + 1) * 64);
    const unsigned char* As = smem + (t & 1) * BUF;
    const unsigned char* Bs = As + ASZ;
    i32x8 af[FM], bfr[FN];
#pragma unroll
    for (int mi = 0; mi < FM; ++mi) {
      int row = wm * (BM / 2) + mi * 32 + l31;
      int s = (row >> 1) & 3;
      int c0 = (2 * h) ^ s, c1 = (2 * h + 1) ^ s;   // two 16B chunks = 32B of k
      uint4 u0 = *(const uint4*)&As[row * 64 + c0 * 16];
      uint4 u1 = *(const uint4*)&As[row * 64 + c1 * 16];
      af[mi][0] = (int)u0.x; af[mi][1] = (int)u0.y; af[mi][2] = (int)u0.z; af[mi][3] = (int)u0.w;
      af[mi][4] = (int)u1.x; af[mi][5] = (int)u1.y; af[mi][6] = (int)u1.z; af[mi][7] = (int)u1.w;
    }
#pragma unroll
    for (int ni = 0; ni < FN; ++ni) {
      int row = wn * (BN / 2) + ni * 32 + l31;
      int s = (row >> 1) & 3;
      int c0 = (2 * h) ^ s, c1 = (2 * h + 1) ^ s;
      uint4 u0 = *(const uint4*)&Bs[row * 64 + c0 * 16];
      uint4 u1 = *(const uint4*)&Bs[row * 64 + c1 * 16];
      bfr[ni][0] = (int)u0.x; bfr[ni][1] = (int)u0.y; bfr[ni][2] = (int)u0.z; bfr[ni][3] = (int)u0.w;
      bfr[ni][4] = (int)u1.x; bfr[ni][5] = (int)u1.y; bfr[ni][6] = (int)u1.z; bfr[ni][7] = (int)u1.w;
    }
#pragma unroll
    for (int mi = 0; mi < FM; ++mi)
#pragma unroll
      for (int ni = 0; ni < FN; ++ni)
        acc[mi][ni] = __builtin_amdgcn_mfma_scale_f32_32x32x64_f8f6f4(
            af[mi], bfr[ni], acc[mi][ni],
            0, 0,                       // cbsz/blgp = fp8 e4m3
            0, 0x7f7f7f7f,              // scale_a: e8m0 = 1.0
            0, 0x7f7f7f7f);             // scale_b: e8m0 = 1.0
    __syncthreads();
  }
}

// fp8 16x16 C/D layout (measured m89/m91): col = lane&15, row = (lane>>4)*4 + reg.

// ---------------------------------------------------------------------------
// QKV GEMM: X[16384][512] @ Wqkv^T.  All outputs staged in LDS and written
// as coalesced 16B chunks: q8/k8 as [token][c] rows, v transposed to
// vt8[b][c][n] rows.  Bias folded into the staging conversion.
// ---------------------------------------------------------------------------
__global__ __launch_bounds__(256) void k_gemm_qkv(
    const __bf16* __restrict__ X, const __bf16* __restrict__ Wt,
    const float* __restrict__ bias, unsigned char* __restrict__ q8,
    unsigned char* __restrict__ k8, unsigned char* __restrict__ vt8)
{
  __shared__ __align__(16) __bf16 smem[2 * (128 * 32 + 128 * 32)];  // 32 KB dbuf
  f32x4 acc[4][4];
#pragma unroll
  for (int i = 0; i < 4; ++i)
#pragma unroll
    for (int j = 0; j < 4; ++j)
#pragma unroll
      for (int r = 0; r < 4; ++r) acc[i][j][r] = 0.f;
  const int m0 = blockIdx.x * 128, n0 = blockIdx.y * 128;
  gemm_core_db<128, 128>(X, Wt, 512, m0, n0, smem, acc);

  const int lane = threadIdx.x & 63, wave = threadIdx.x >> 6;
  const int wm = wave >> 1, wn = wave & 1, l15 = lane & 15, l4 = lane >> 4;

  // Stage the 128x128 fp8 patch in LDS (stride 144: proven conflict-light),
  // then store coalesced.  Core's final barrier makes smem safe to reuse.
  unsigned char* t8 = (unsigned char*)smem;  // 128*144 = 18432 B <= 32768
  if (blockIdx.y < 8) {
    // q or k: patch[token_local][c_local], no transpose
#pragma unroll
    for (int mi = 0; mi < 4; ++mi)
#pragma unroll
      for (int ni = 0; ni < 4; ++ni) {
        int lcol = wn * 64 + ni * 16 + l15;
        float bb = bias[n0 + lcol];
#pragma unroll
        for (int r = 0; r < 4; ++r) {
          int lrow = wm * 64 + mi * 16 + l4 * 4 + r;
          t8[lrow * 144 + lcol] = f2fp8(acc[mi][ni][r] + bb);
        }
      }
    __syncthreads();
    unsigned char* dst = (blockIdx.y < 4) ? q8 : k8;
    const int c0 = (blockIdx.y < 4) ? n0 : n0 - 512;
#pragma unroll
    for (int j = 0; j < 4; ++j) {
      int idx = j * 256 + threadIdx.x;
      int crow = idx >> 3, ccol = (idx & 7) * 16;
      uint4 v = *(const uint4*)&t8[crow * 144 + ccol];
      *(uint4*)&dst[(size_t)(m0 + crow) * 512 + c0 + ccol] = v;
    }
  } else {
    // v: patch transposed to [c_local][token_local]
#pragma unroll
    for (int mi = 0; mi < 4; ++mi)
#pragma unroll
      for (int ni = 0; ni < 4; ++ni) {
        int c_l = wn * 64 + ni * 16 + l15;
        float bb = bias[n0 + c_l];
#pragma unroll
        for (int r = 0; r < 4; ++r) {
          int n_l = wm * 64 + mi * 16 + l4 * 4 + r;
          t8[c_l * 144 + n_l] = f2fp8(acc[mi][ni][r] + bb);
        }
      }
    __syncthreads();
    const int b = m0 >> 12, nst = m0 & 4095;
    const int c0 = n0 - 1024;
#pragma unroll
    for (int j = 0; j < 4; ++j) {
      int idx = j * 256 + threadIdx.x;
      int crow = idx >> 3, ccol = (idx & 7) * 16;
      uint4 v = *(const uint4*)&t8[crow * 144 + ccol];
      *(uint4*)&vt8[((size_t)b * 512 + c0 + crow) * 4096 + nst + ccol] = v;
    }
  }
}

// ---------------------------------------------------------------------------
// Scores GEMM (fp8 x fp8, BK=64, 2-phase dbuf) + max-free softmax numerator,
// batched over z: P[b][n][m] = exp(q.k) stored fp8 e4m3; lsum fp32 row sums.
// Epilogue: exp+rowsum in regs, then ONE-pass transpose into a 128x144 LDS
// tile (reuses the 32KB dbuf smem; 2 barriers instead of 8), 16B stores.
// ---------------------------------------------------------------------------
__global__ __launch_bounds__(256) void k_gemm_s(
    const unsigned char* __restrict__ qall, const unsigned char* __restrict__ kall,
    unsigned char* __restrict__ S8all, float* __restrict__ lsum)
{
  __shared__ __align__(16) unsigned char smem[32768];  // 2 x (8KB As + 8KB Bs)
  f32x4 acc[4][4];
#pragma unroll
  for (int i = 0; i < 4; ++i)
#pragma unroll
    for (int j = 0; j < 4; ++j)
#pragma unroll
      for (int r = 0; r < 4; ++r) acc[i][j][r] = 0.f;

  // supertile swizzle: 1024 blocks/batch -> 16 groups of 64 (8x8)
  const int b = blockIdx.z;
  const int flat = blockIdx.x + (blockIdx.y << 5);
  const int gx = flat & 7, gy = (flat >> 3) & 7, grp = flat >> 6;
  const int bx = (grp & 3) * 8 + gx, by = (grp >> 2) * 8 + gy;
  const int m0 = bx * 128, n0 = by * 128;

  const unsigned char* q = qall + (size_t)b * 4096 * 512;
  const unsigned char* k = kall + (size_t)b * 4096 * 512;
  unsigned char* S8 = S8all + (size_t)b * 4096 * 4096;
  gemm_core_fp8_db<128, 128>(q, k, 512, m0, n0, smem, acc);

  const int lane = threadIdx.x & 63, wave = threadIdx.x >> 6;
  const int wm = wave >> 1, wn = wave & 1, l15 = lane & 15, l4 = lane >> 4;

  // exp in place + fp32 row-sum atomics (pre-fp8-rounding; unbiased)
#pragma unroll
  for (int mi = 0; mi < 4; ++mi) {
    float rsum[4] = {0.f, 0.f, 0.f, 0.f};
#pragma unroll
    for (int ni = 0; ni < 4; ++ni)
#pragma unroll
      for (int r = 0; r < 4; ++r) {
        float p = __expf(acc[mi][ni][r]);
        acc[mi][ni][r] = p;
        rsum[r] += p;
      }
#pragma unroll
    for (int r = 0; r < 4; ++r) {
#pragma unroll
      for (int off = 1; off < 16; off <<= 1) rsum[r] += __shfl_xor(rsum[r], off, 64);
      if (l15 == 0) {
        int grow = m0 + wm * 64 + mi * 16 + l4 * 4 + r;
        atomicAdd(&lsum[b * 4096 + grow], rsum[r]);
      }
    }
  }

  // One-pass transpose: all waves convert into t8[128][144], then store.
  // (core's final barrier already synced all LDS readers; safe to overwrite)
  unsigned char* t8 = smem;  // 128*144 = 18432 B <= 32768
#pragma unroll
  for (int mi = 0; mi < 4; ++mi)
#pragma unroll
    for (int ni = 0; ni < 4; ++ni) {
      int lcol = wn * 64 + ni * 16 + l15;
#pragma unroll
      for (int r = 0; r < 4; ++r) {
        int lrow = wm * 64 + mi * 16 + l4 * 4 + r;
        t8[lrow * 144 + lcol] = f2fp8(acc[mi][ni][r]);
      }
    }
  __syncthreads();
  // store 128 rows x 128 B: 1024 chunks of 16B, 4 per thread
#pragma unroll
  for (int j = 0; j < 4; ++j) {
    int idx = j * 256 + threadIdx.x;
    int crow = idx >> 3, ccol = (idx & 7) * 16;
    uint4 v = *(const uint4*)&t8[crow * 144 + ccol];
    *(uint4*)&S8[(size_t)(m0 + crow) * 4096 + n0 + ccol] = v;
  }
}

// ---------------------------------------------------------------------------
// PV GEMM (MX fp8 32x32x64, BK=64, 2-phase dbuf), batched over z:
// O[b,n,c] = (sum_m P[b,n,m] * vt[b,c,m]) / l[b,n].
// ---------------------------------------------------------------------------
__global__ __launch_bounds__(256) void k_gemm_pv(
    const unsigned char* __restrict__ S8all, const unsigned char* __restrict__ vt8all,
    const float* __restrict__ lsum, __bf16* __restrict__ attn)
{
  __shared__ __align__(16) unsigned char smem[32768];  // 2 x (8KB As + 8KB Bs)
  f32x16 acc[2][2];
#pragma unroll
  for (int i = 0; i < 2; ++i)
#pragma unroll
    for (int j = 0; j < 2; ++j)
#pragma unroll
      for (int r = 0; r < 16; ++r) acc[i][j][r] = 0.f;
  const int b = blockIdx.z;
  const unsigned char* P = S8all + (size_t)b * 4096 * 4096;
  const unsigned char* V = vt8all + (size_t)b * 512 * 4096;
  __bf16* O = attn + (size_t)b * 4096 * 512;
  const int m0 = blockIdx.x * 128, n0 = blockIdx.y * 128;
  gemm_core_mx32_db<128, 128>(P, V, 4096, m0, n0, smem, acc);

  const int lane = threadIdx.x & 63, wave = threadIdx.x >> 6;
  const int wm = wave >> 1, wn = wave & 1, l31 = lane & 31, h = lane >> 5;
#pragma unroll
  for (int mi = 0; mi < 2; ++mi)
#pragma unroll
    for (int ni = 0; ni < 2; ++ni) {
      int gcol = n0 + wn * 64 + ni * 32 + l31;
#pragma unroll
      for (int r = 0; r < 16; ++r) {
        int grow = m0 + wm * 64 + mi * 32 + (r & 3) + 8 * (r >> 2) + 4 * h;
        float inv = 1.f / lsum[b * 4096 + grow];
        O[(size_t)grow * 512 + gcol] = (__bf16)(acc[mi][ni][r] * inv);
      }
    }
}

// ---------------------------------------------------------------------------
// Output projection + bias + residual, fp32 store to d_out.
// ---------------------------------------------------------------------------
__global__ __launch_bounds__(256) void k_gemm_out(
    const __bf16* __restrict__ A, const __bf16* __restrict__ Wot,
    const float* __restrict__ bo, const float* __restrict__ resid, float* __restrict__ out)
{
  __shared__ __align__(16) __bf16 smem[2 * (128 * 32 + 128 * 32)];  // 32 KB dbuf
  f32x4 acc[4][4];
#pragma unroll
  for (int i = 0; i < 4; ++i)
#pragma unroll
    for (int j = 0; j < 4; ++j)
#pragma unroll
      for (int r = 0; r < 4; ++r) acc[i][j][r] = 0.f;
  const int m0 = blockIdx.x * 128, n0 = blockIdx.y * 128;
  gemm_core_db<128, 128>(A, Wot, 512, m0, n0, smem, acc);

  const int lane = threadIdx.x & 63, wave = threadIdx.x >> 6;
  const int wm = wave >> 1, wn = wave & 1, l15 = lane & 15, l4 = lane >> 4;
#pragma unroll
  for (int mi = 0; mi < 4; ++mi)
#pragma unroll
    for (int ni = 0; ni < 4; ++ni) {
      int gcol = n0 + wn * 64 + ni * 16 + l15;
      float bb = bo[gcol];
#pragma unroll
      for (int r = 0; r < 4; ++r) {
        int grow = m0 + wm * 64 + mi * 16 + l4 * 4 + r;
        size_t idx = (size_t)grow * 512 + gcol;
        out[idx] = acc[mi][ni][r] + bb + resid[idx];
      }
    }
}

// ---------------------------------------------------------------------------
extern "C" void kernel_launch(void* const* d_in, const int* in_sizes, int n_in,
                              void* d_out, int out_size, void* d_ws, size_t ws_size,
                              hipStream_t stream)
{
  const float* x     = (const float*)d_in[0];
  const float* gamma = (const float*)d_in[1];
  const float* beta  = (const float*)d_in[2];
  const float* wq    = (const float*)d_in[3];
  const float* bq    = (const float*)d_in[4];
  const float* wk    = (const float*)d_in[5];
  const float* bk    = (const float*)d_in[6];
  const float* wv    = (const float*)d_in[7];
  const float* bv    = (const float*)d_in[8];
  const float* wo    = (const float*)d_in[9];
  const float* bo    = (const float*)d_in[10];
  float* out = (float*)d_out;

  char* ws = (char*)d_ws;
  size_t off = 0;
  auto alloc = [&](size_t bytes) -> char* {
    char* p = ws + off;
    off += (bytes + 255) & ~(size_t)255;
    return p;
  };
  float*  meanv   = (float*)alloc(128 * 4);
  float*  rstdv   = (float*)alloc(128 * 4);
  __bf16* x16     = (__bf16*)alloc(16384ull * 512 * 2);   // 16 MB
  __bf16* wqkvt   = (__bf16*)alloc(1536ull * 512 * 2);    // 1.5 MB
  float*  biasqkv = (float*)alloc(1536 * 4);
  __bf16* wot     = (__bf16*)alloc(512ull * 512 * 2);     // 0.5 MB
  float*  lsum    = (float*)alloc(16384ull * 4);          // 64 KB row sums
  unsigned char* q8  = (unsigned char*)alloc(16384ull * 512);     // 8 MB fp8 Q
  unsigned char* k8  = (unsigned char*)alloc(16384ull * 512);     // 8 MB fp8 K
  unsigned char* vt8 = (unsigned char*)alloc(16384ull * 512);     // 8 MB fp8 V^T
  __bf16* attn    = (__bf16*)alloc(16384ull * 512 * 2);   // 16 MB
  unsigned char* S8 = (unsigned char*)alloc(4ull * 4096 * 4096);  // 64 MB fp8 exp(scores)
  // total ~122 MB

  k_gnstats<<<dim3(128), dim3(256), 0, stream>>>(x, meanv, rstdv);
  k_norm<<<dim3(8192), dim3(256), 0, stream>>>(x, meanv, rstdv, gamma, beta, x16);
  k_prep<<<dim3(4166), dim3(256), 0, stream>>>(wq, bq, wk, bk, wv, bv, wo,
                                               wqkvt, biasqkv, wot, lsum);
  k_gemm_qkv<<<dim3(128, 12), dim3(256), 0, stream>>>(x16, wqkvt, biasqkv, q8, k8, vt8);
  k_gemm_s<<<dim3(32, 32, 4), dim3(256), 0, stream>>>(q8, k8, S8, lsum);
  k_gemm_pv<<<dim3(32, 4, 4), dim3(256), 0, stream>>>(S8, vt8, lsum, attn);
  k_gemm_out<<<dim3(128, 4), dim3(256), 0, stream>>>(attn, wot, bo, x, out);
}